// Round 3
// baseline (250.901 us; speedup 1.0000x reference)
//
#include <hip/hip_runtime.h>

// LiteralE fused gather + 4 batched matvecs + gated update.
// out[b,i] = Z*H + (1-Z)*e_idx, Z = sigmoid(Wze·e + Wzl·l + bias),
// H = tanh(Whe·e + Whl·l), gathered at n = index[b].
//
// 16 lanes per weight row (4 rows/wave/pass, 8 passes), 4-step shfl_xor
// reduce. Per-wave load instructions are contiguous 256B×4 segments.
// x fragments loaded per-lane from global (no barrier ahead of the weight
// stream). 4 batch elements per block to amortize prologue/launch.

constexpr int H_DIM = 128;
constexpr int N_D   = 64;
constexpr int ELEMS = 4;

__global__ __launch_bounds__(256) void literal_e_fused(
    const float* __restrict__ e,
    const float* __restrict__ l,
    const float* __restrict__ W_ze,
    const float* __restrict__ W_zl,
    const float* __restrict__ W_he,
    const float* __restrict__ W_hl,
    const float* __restrict__ bias,
    const int*  __restrict__ index,
    float* __restrict__ out)
{
    const int tid  = threadIdx.x;
    const int wave = tid >> 6;         // 0..3
    const int lane = tid & 63;
    const int g    = lane >> 4;        // row offset within wave's 4-row group
    const int j    = lane & 15;        // column-chunk lane

    __shared__ float se[H_DIM];
    __shared__ float az_s[H_DIM];
    __shared__ float ah_s[H_DIM];
    __shared__ float sb[H_DIM];

    if (tid < H_DIM) sb[tid] = bias[tid];

    const long long base = (long long)blockIdx.x * ELEMS;
    long long n_next = (long long)index[base];   // uniform scalar load

    for (int it = 0; it < ELEMS; ++it) {
        const long long n  = n_next;
        if (it + 1 < ELEMS) n_next = (long long)index[base + it + 1];
        const long long bi = base + it;

        // Row-invariant x fragments, straight from global (lane-contiguous).
        const float4* ep = reinterpret_cast<const float4*>(e + n * H_DIM);
        const float4 xe0 = ep[j];          // cols 4j..4j+3
        const float4 xe1 = ep[j + 16];     // cols 64+4j..64+4j+3
        const float4 xl  = reinterpret_cast<const float4*>(l + n * N_D)[j];
        if (tid < H_DIM) se[tid] = e[n * H_DIM + tid];   // epilogue copy

        const float4* wze = reinterpret_cast<const float4*>(W_ze + n * (size_t)(H_DIM * H_DIM));
        const float4* whe = reinterpret_cast<const float4*>(W_he + n * (size_t)(H_DIM * H_DIM));
        const float4* wzl = reinterpret_cast<const float4*>(W_zl + n * (size_t)(H_DIM * N_D));
        const float4* whl = reinterpret_cast<const float4*>(W_hl + n * (size_t)(H_DIM * N_D));

        #pragma unroll 4
        for (int pass = 0; pass < 8; ++pass) {
            const int r = pass * 16 + wave * 4 + g;   // row 0..127

            const float4 a0 = wze[r * 32 + j];        // cols 4j..4j+3
            const float4 a1 = wze[r * 32 + j + 16];   // cols 64+4j..
            const float4 b0 = whe[r * 32 + j];
            const float4 b1 = whe[r * 32 + j + 16];
            const float4 c0 = wzl[r * 16 + j];
            const float4 d0 = whl[r * 16 + j];

            float pz = fmaf(a0.x, xe0.x, fmaf(a0.y, xe0.y, fmaf(a0.z, xe0.z, a0.w * xe0.w)));
            pz = fmaf(a1.x, xe1.x, fmaf(a1.y, xe1.y, fmaf(a1.z, xe1.z, fmaf(a1.w, xe1.w, pz))));
            pz = fmaf(c0.x, xl.x,  fmaf(c0.y, xl.y,  fmaf(c0.z, xl.z,  fmaf(c0.w, xl.w,  pz))));

            float ph = fmaf(b0.x, xe0.x, fmaf(b0.y, xe0.y, fmaf(b0.z, xe0.z, b0.w * xe0.w)));
            ph = fmaf(b1.x, xe1.x, fmaf(b1.y, xe1.y, fmaf(b1.z, xe1.z, fmaf(b1.w, xe1.w, ph))));
            ph = fmaf(d0.x, xl.x,  fmaf(d0.y, xl.y,  fmaf(d0.z, xl.z,  fmaf(d0.w, xl.w,  ph))));

            // Reduce across the 16-lane group (lane j==0 ends with the sum).
            #pragma unroll
            for (int m = 1; m <= 8; m <<= 1) {
                pz += __shfl_xor(pz, m, 64);
                ph += __shfl_xor(ph, m, 64);
            }
            if (j == 0) { az_s[r] = pz; ah_s[r] = ph; }
        }
        __syncthreads();

        if (tid < H_DIM) {
            const float zg = 1.0f / (1.0f + __expf(-(az_s[tid] + sb[tid])));
            const float hc = tanhf(ah_s[tid]);
            out[bi * H_DIM + tid] = zg * hc + (1.0f - zg) * se[tid];
        }
        __syncthreads();   // protect se/az_s/ah_s before next element
    }
}

extern "C" void kernel_launch(void* const* d_in, const int* in_sizes, int n_in,
                              void* d_out, int out_size, void* d_ws, size_t ws_size,
                              hipStream_t stream) {
    const float* e    = (const float*)d_in[0];
    const float* l    = (const float*)d_in[1];
    const float* W_ze = (const float*)d_in[2];
    const float* W_zl = (const float*)d_in[3];
    const float* W_he = (const float*)d_in[4];
    const float* W_hl = (const float*)d_in[5];
    const float* bias = (const float*)d_in[6];
    const int*   idx  = (const int*)d_in[7];
    float* out = (float*)d_out;

    const int B = in_sizes[7];   // 8192
    const int nblocks = B / ELEMS;

    literal_e_fused<<<dim3(nblocks), dim3(256), 0, stream>>>(
        e, l, W_ze, W_zl, W_he, W_hl, bias, idx, out);
}

// Round 4
// 207.101 us; speedup vs baseline: 1.2115x; 1.2115x over previous
//
#include <hip/hip_runtime.h>

// LiteralE: out[b] = f(index[b]) where f(n) = Z*H + (1-Z)*e[n],
// Z = sigmoid(W_ze[n]·e[n] + W_zl[n]·l[n] + b), H = tanh(W_he[n]·e[n] + W_hl[n]·l[n]).
//
// out depends ONLY on n -> dedupe: compute f(n) once per *used* entity
// (streaming, XCD-chunked weight reads), then gather out[b] = uout[index[b]].
// Cuts requested weight traffic from B*192KB (1.58 GB) to unique*192KB (~1.07 GB),
// which is the floor on the capped L2-miss/HBM path.

constexpr int H_DIM = 128;
constexpr int N_D   = 64;
constexpr int N_ENT = 10000;

__global__ void k_zero_used(int* used) {
    const int i = blockIdx.x * blockDim.x + threadIdx.x;
    if (i < N_ENT) used[i] = 0;
}

__global__ void k_mark_used(const int* __restrict__ index, int* __restrict__ used, int B) {
    const int b = blockIdx.x * blockDim.x + threadIdx.x;
    if (b < B) used[index[b]] = 1;
}

// One block per entity id (XCD-chunk swizzled). Early-out if unused.
__global__ __launch_bounds__(256) void k_compute_unique(
    const float* __restrict__ e,
    const float* __restrict__ l,
    const float* __restrict__ W_ze,
    const float* __restrict__ W_zl,
    const float* __restrict__ W_he,
    const float* __restrict__ W_hl,
    const float* __restrict__ bias,
    const int*  __restrict__ used,
    float* __restrict__ uout)
{
    // 10000 % 8 == 0: XCD k streams entities [k*1250, (k+1)*1250).
    const int bid = blockIdx.x;
    const long long n = (long long)((bid & 7) * (N_ENT / 8) + (bid >> 3));
    if (!used[n]) return;

    const int tid  = threadIdx.x;
    const int wave = tid >> 6;
    const int lane = tid & 63;
    const int g    = lane >> 4;        // row within wave's 4-row group
    const int j    = lane & 15;        // column-chunk lane

    __shared__ float az_s[H_DIM];
    __shared__ float ah_s[H_DIM];

    const float4* ep = reinterpret_cast<const float4*>(e + n * H_DIM);
    const float4 xe0 = ep[j];
    const float4 xe1 = ep[j + 16];
    const float4 xl  = reinterpret_cast<const float4*>(l + n * N_D)[j];

    const float4* wze = reinterpret_cast<const float4*>(W_ze + n * (size_t)(H_DIM * H_DIM));
    const float4* whe = reinterpret_cast<const float4*>(W_he + n * (size_t)(H_DIM * H_DIM));
    const float4* wzl = reinterpret_cast<const float4*>(W_zl + n * (size_t)(H_DIM * N_D));
    const float4* whl = reinterpret_cast<const float4*>(W_hl + n * (size_t)(H_DIM * N_D));

    #pragma unroll 4
    for (int pass = 0; pass < 8; ++pass) {
        const int r = pass * 16 + wave * 4 + g;   // row 0..127

        const float4 a0 = wze[r * 32 + j];
        const float4 a1 = wze[r * 32 + j + 16];
        const float4 b0 = whe[r * 32 + j];
        const float4 b1 = whe[r * 32 + j + 16];
        const float4 c0 = wzl[r * 16 + j];
        const float4 d0 = whl[r * 16 + j];

        float pz = fmaf(a0.x, xe0.x, fmaf(a0.y, xe0.y, fmaf(a0.z, xe0.z, a0.w * xe0.w)));
        pz = fmaf(a1.x, xe1.x, fmaf(a1.y, xe1.y, fmaf(a1.z, xe1.z, fmaf(a1.w, xe1.w, pz))));
        pz = fmaf(c0.x, xl.x,  fmaf(c0.y, xl.y,  fmaf(c0.z, xl.z,  fmaf(c0.w, xl.w,  pz))));

        float ph = fmaf(b0.x, xe0.x, fmaf(b0.y, xe0.y, fmaf(b0.z, xe0.z, b0.w * xe0.w)));
        ph = fmaf(b1.x, xe1.x, fmaf(b1.y, xe1.y, fmaf(b1.z, xe1.z, fmaf(b1.w, xe1.w, ph))));
        ph = fmaf(d0.x, xl.x,  fmaf(d0.y, xl.y,  fmaf(d0.z, xl.z,  fmaf(d0.w, xl.w,  ph))));

        #pragma unroll
        for (int m = 1; m <= 8; m <<= 1) {
            pz += __shfl_xor(pz, m, 64);
            ph += __shfl_xor(ph, m, 64);
        }
        if (j == 0) { az_s[r] = pz; ah_s[r] = ph; }
    }
    __syncthreads();

    if (tid < H_DIM) {
        const float zg = 1.0f / (1.0f + __expf(-(az_s[tid] + bias[tid])));
        const float hc = tanhf(ah_s[tid]);
        const float ei = e[n * H_DIM + tid];
        uout[n * H_DIM + tid] = zg * hc + (1.0f - zg) * ei;
    }
}

__global__ void k_gather(const int* __restrict__ index,
                         const float* __restrict__ uout,
                         float* __restrict__ out, int B)
{
    const int i = blockIdx.x * blockDim.x + threadIdx.x;   // one float4 each
    if (i < B * (H_DIM / 4)) {
        const int b = i >> 5;
        const int c = i & 31;
        const long long n = (long long)index[b];
        reinterpret_cast<float4*>(out)[(size_t)b * 32 + c] =
            reinterpret_cast<const float4*>(uout)[n * 32 + c];
    }
}

// ---- Fallback (round-3 monolithic) if ws_size is too small ----
constexpr int ELEMS = 4;
__global__ __launch_bounds__(256) void literal_e_fused(
    const float* __restrict__ e, const float* __restrict__ l,
    const float* __restrict__ W_ze, const float* __restrict__ W_zl,
    const float* __restrict__ W_he, const float* __restrict__ W_hl,
    const float* __restrict__ bias, const int* __restrict__ index,
    float* __restrict__ out)
{
    const int tid  = threadIdx.x;
    const int wave = tid >> 6;
    const int lane = tid & 63;
    const int g    = lane >> 4;
    const int j    = lane & 15;

    __shared__ float se[H_DIM];
    __shared__ float az_s[H_DIM];
    __shared__ float ah_s[H_DIM];

    const long long base = (long long)blockIdx.x * ELEMS;
    for (int it = 0; it < ELEMS; ++it) {
        const long long n  = (long long)index[base + it];
        const long long bi = base + it;
        const float4* ep = reinterpret_cast<const float4*>(e + n * H_DIM);
        const float4 xe0 = ep[j];
        const float4 xe1 = ep[j + 16];
        const float4 xl  = reinterpret_cast<const float4*>(l + n * N_D)[j];
        if (tid < H_DIM) se[tid] = e[n * H_DIM + tid];

        const float4* wze = reinterpret_cast<const float4*>(W_ze + n * (size_t)(H_DIM * H_DIM));
        const float4* whe = reinterpret_cast<const float4*>(W_he + n * (size_t)(H_DIM * H_DIM));
        const float4* wzl = reinterpret_cast<const float4*>(W_zl + n * (size_t)(H_DIM * N_D));
        const float4* whl = reinterpret_cast<const float4*>(W_hl + n * (size_t)(H_DIM * N_D));

        #pragma unroll 4
        for (int pass = 0; pass < 8; ++pass) {
            const int r = pass * 16 + wave * 4 + g;
            const float4 a0 = wze[r * 32 + j];
            const float4 a1 = wze[r * 32 + j + 16];
            const float4 b0 = whe[r * 32 + j];
            const float4 b1 = whe[r * 32 + j + 16];
            const float4 c0 = wzl[r * 16 + j];
            const float4 d0 = whl[r * 16 + j];
            float pz = fmaf(a0.x, xe0.x, fmaf(a0.y, xe0.y, fmaf(a0.z, xe0.z, a0.w * xe0.w)));
            pz = fmaf(a1.x, xe1.x, fmaf(a1.y, xe1.y, fmaf(a1.z, xe1.z, fmaf(a1.w, xe1.w, pz))));
            pz = fmaf(c0.x, xl.x,  fmaf(c0.y, xl.y,  fmaf(c0.z, xl.z,  fmaf(c0.w, xl.w,  pz))));
            float ph = fmaf(b0.x, xe0.x, fmaf(b0.y, xe0.y, fmaf(b0.z, xe0.z, b0.w * xe0.w)));
            ph = fmaf(b1.x, xe1.x, fmaf(b1.y, xe1.y, fmaf(b1.z, xe1.z, fmaf(b1.w, xe1.w, ph))));
            ph = fmaf(d0.x, xl.x,  fmaf(d0.y, xl.y,  fmaf(d0.z, xl.z,  fmaf(d0.w, xl.w,  ph))));
            #pragma unroll
            for (int m = 1; m <= 8; m <<= 1) {
                pz += __shfl_xor(pz, m, 64);
                ph += __shfl_xor(ph, m, 64);
            }
            if (j == 0) { az_s[r] = pz; ah_s[r] = ph; }
        }
        __syncthreads();
        if (tid < H_DIM) {
            const float zg = 1.0f / (1.0f + __expf(-(az_s[tid] + bias[tid])));
            const float hc = tanhf(ah_s[tid]);
            out[bi * H_DIM + tid] = zg * hc + (1.0f - zg) * se[tid];
        }
        __syncthreads();
    }
}

extern "C" void kernel_launch(void* const* d_in, const int* in_sizes, int n_in,
                              void* d_out, int out_size, void* d_ws, size_t ws_size,
                              hipStream_t stream) {
    const float* e    = (const float*)d_in[0];
    const float* l    = (const float*)d_in[1];
    const float* W_ze = (const float*)d_in[2];
    const float* W_zl = (const float*)d_in[3];
    const float* W_he = (const float*)d_in[4];
    const float* W_hl = (const float*)d_in[5];
    const float* bias = (const float*)d_in[6];
    const int*   idx  = (const int*)d_in[7];
    float* out = (float*)d_out;

    const int B = in_sizes[7];   // 8192

    const size_t uout_bytes = (size_t)N_ENT * H_DIM * sizeof(float);   // 5.12 MB
    const size_t need = uout_bytes + (size_t)N_ENT * sizeof(int);

    if (ws_size >= need) {
        float* uout = (float*)d_ws;
        int*   used = (int*)((char*)d_ws + uout_bytes);

        k_zero_used<<<dim3((N_ENT + 255) / 256), dim3(256), 0, stream>>>(used);
        k_mark_used<<<dim3((B + 255) / 256), dim3(256), 0, stream>>>(idx, used, B);
        k_compute_unique<<<dim3(N_ENT), dim3(256), 0, stream>>>(
            e, l, W_ze, W_zl, W_he, W_hl, bias, used, uout);
        k_gather<<<dim3((B * (H_DIM / 4) + 255) / 256), dim3(256), 0, stream>>>(
            idx, uout, out, B);
    } else {
        literal_e_fused<<<dim3(B / ELEMS), dim3(256), 0, stream>>>(
            e, l, W_ze, W_zl, W_he, W_hl, bias, idx, out);
    }
}